// Round 12
// baseline (191.059 us; speedup 1.0000x reference)
//
#include <hip/hip_runtime.h>

// RecallK via bf16 hi/lo split on matrix cores.
// dot(x_i,x_j) ~= hi.hi + lo.hi + hi.lo  (lo.lo dropped: ~2e-5 distance noise).
// argmin_j (sq_j - 2*dot) per row == argmin of ref distmat (row-constant sq_i dropped).
// R12: counted-vmcnt pipeline. R10's cycle budget shows ~60% of time is the per-tile
// __syncthreads GLDS drain (compiler emits vmcnt(0) before s_barrier; per-tile compute
// ~600 cyc < GLDS round-trip ~500-900 cyc). New sync structure (T3/T4):
//   - triple-buffered B tiles; stage tile t+2 each iter (depth-2 prefetch)
//   - raw s_barrier + asm vmcnt(8) (never 0 mid-loop) + sched_barrier(0) fences
//   - sq staged to LDS in prologue -> epilogue sq reads are lgkm (ds_read), keeping
//     the vmem queue = pure GLDS so counted vmcnt stays exact (no compiler drains)
// Race-freedom: stage at iter t writes the buffer read at iter t-1; its readers all
// passed the top-of-t barrier (ds_reads consumed via lgkm waits before MFMA issue,
// hence before barrier arrival). Compute kernel body = R10 verbatim (absmax 0).
// R11's C-init-fold + packed-tag epilogue withdrawn (unexplained full-randomization
// failure -> both novel pieces pulled per theory-first discipline).
// P16 layout (A and B frags of mfma_f32_16x16x32_bf16 read lane-linear 16B chunks):
//   chunk(g16,ks,l) = (g16*4+ks)*64+l  holds  X[g16*16+(l&15)][ks*32+(l>>4)*8 .. +8]

typedef __bf16 bf16x8 __attribute__((ext_vector_type(8)));
typedef float f32x4 __attribute__((ext_vector_type(4)));

#define NN 16384
#define MFMA16(A, B, C) __builtin_amdgcn_mfma_f32_16x16x32_bf16(A, B, C, 0, 0, 0)
#define GLDS(gsrc, ldst)                                                              \
  __builtin_amdgcn_global_load_lds((const __attribute__((address_space(1))) void*)(gsrc), \
                                   (__attribute__((address_space(3))) void*)(ldst), 16, 0, 0)

// --- per-row squared norms, exact fp32 (one wave per row) ---
__global__ __launch_bounds__(256) void sq_kernel(const float* __restrict__ feat,
                                                 float* __restrict__ sq) {
  int gid = blockIdx.x * 256 + threadIdx.x;
  int row = gid >> 6;
  int lane = threadIdx.x & 63;
  float2 v = reinterpret_cast<const float2*>(feat + (size_t)row * 128)[lane];
  float s = v.x * v.x + v.y * v.y;
#pragma unroll
  for (int off = 32; off > 0; off >>= 1) s += __shfl_xor(s, off, 64);
  if (lane == 0) sq[row] = s;
}

// --- fp32 -> (hi,lo) bf16 banks in 16-row-group MFMA-chunk order ---
__global__ __launch_bounds__(256) void convert_kernel(const float* __restrict__ feat,
                                                      bf16x8* __restrict__ Ph,
                                                      bf16x8* __restrict__ Pl) {
  int chunk = blockIdx.x * 256 + threadIdx.x;  // 262144 chunks
  int l = chunk & 63;
  int ks = (chunk >> 6) & 3;
  int g = chunk >> 8;                          // 0..1023 (16-row groups)
  int row = g * 16 + (l & 15);
  int k0 = ks * 32 + (l >> 4) * 8;
  const float4* s = reinterpret_cast<const float4*>(feat + (size_t)row * 128 + k0);
  float4 v0 = s[0], v1 = s[1];
  float xs[8] = {v0.x, v0.y, v0.z, v0.w, v1.x, v1.y, v1.z, v1.w};
  bf16x8 hv, lv;
#pragma unroll
  for (int e = 0; e < 8; ++e) {
    float x = xs[e];
    __bf16 h = (__bf16)x;
    hv[e] = h;
    lv[e] = (__bf16)(x - (float)h);
  }
  Ph[chunk] = hv;
  Pl[chunk] = lv;
}

// --- main: 1024 blocks (128 panels x 8 slices), 4 waves x 32 rows, 32-col tiles ---
__global__ __launch_bounds__(256, 2) void nn_mfma(const bf16x8* __restrict__ Ph,
                                                  const bf16x8* __restrict__ Pl,
                                                  const float* __restrict__ sq,
                                                  float* __restrict__ bestD,
                                                  int* __restrict__ bestI) {
  __shared__ bf16x8 BhL[3][512];  // 3 bufs x 8 KB  (tile = 32 cols x 128 k, hi bank)
  __shared__ bf16x8 BlL[3][512];  // 3 bufs x 8 KB  (lo bank)
  __shared__ float sqL[2048];     // this slice's col norms (8 KB)  -> total 56 KB
  const int bid = blockIdx.x;
  const int slice = bid & 7;       // 2048-col slice; one per XCD (1 MB hi+lo, L2-fit)
  const int panel = bid >> 3;      // 0..127 row-panels of 128 rows
  const int tid = threadIdx.x;
  const int w = tid >> 6;          // wave 0..3
  const int lane = tid & 63;
  const int lq = lane >> 4;        // row-quad selector in C layout
  const int lc = lane & 15;        // col-in-group

  // A: two 16-row groups (32 rows x K=128, hi+lo): 16 frags = 64 VGPR
  bf16x8 Ah0[4], Al0[4], Ah1[4], Al1[4];
  {
    int gA = panel * 8 + w * 2;
#pragma unroll
    for (int ks = 0; ks < 4; ++ks) {
      Ah0[ks] = Ph[(gA * 4 + ks) * 64 + lane];
      Al0[ks] = Pl[(gA * 4 + ks) * 64 + lane];
      Ah1[ks] = Ph[((gA + 1) * 4 + ks) * 64 + lane];
      Al1[ks] = Pl[((gA + 1) * 4 + ks) * 64 + lane];
    }
  }

  // stage one 32-col B tile (hi+lo) into buffer `nbuf`: 16 GLDS, 4 per wave.
  // wave w: bank = w&1, col-16-group cgi = w>>1   (R10 stage, verbatim)
  auto stage = [&](int nbuf, int tt) {
    const int cgi = w >> 1;
    const int gcol = slice * 128 + tt * 2 + cgi;
    const bf16x8* src = (w & 1) ? Pl : Ph;
    bf16x8* dst = ((w & 1) ? &BlL[nbuf][0] : &BhL[nbuf][0]) + cgi * 256;
#pragma unroll
    for (int ks = 0; ks < 4; ++ks) {
      size_t srcoff = ((size_t)((gcol * 4 + ks) * 64 + lane)) * 16;
      GLDS((const char*)src + srcoff, dst + ks * 64);
    }
  };

  float best0[4], best1[4];
  int bidx0[4], bidx1[4];
#pragma unroll
  for (int r = 0; r < 4; ++r) {
    best0[r] = 3.4e38f; best1[r] = 3.4e38f;
    bidx0[r] = 0; bidx1[r] = 0;
  }

  // prologue: stage tiles 0,1 + slice sq (8 KB = 2 GLDS/wave), heavy barrier once
  stage(0, 0);
  stage(1, 1);
  {
    const float* sqs = sq + slice * 2048;
#pragma unroll
    for (int q = 0; q < 2; ++q) {
      int u = w * 2 + q;  // 8 units x 1 KB
      GLDS((const char*)(sqs + u * 256) + (size_t)lane * 16, &sqL[u * 256]);
    }
  }
  __syncthreads();  // prologue only: drains tiles 0,1 + sqL, syncs all waves

  const int rowlo = panel * 128 + w * 32;  // this wave's 32 rows (32-aligned)
  const int ig0 = rowlo + lq * 4;          // + r = rowgroup0 rows; +16 = rowgroup1

  int cur = 0, stg = 2;
  for (int t = 0; t < 64; ++t) {
    if (t > 0) {
      __builtin_amdgcn_s_barrier();        // all waves done reading buf[stg] (t-1)
      __builtin_amdgcn_sched_barrier(0);
    }
    if (t < 62) {
      stage(stg, t + 2);                   // depth-2 prefetch into the freed buffer
      asm volatile("s_waitcnt vmcnt(8)" ::: "memory");  // tile t certified; t+1,t+2 in flight
    } else if (t == 62) {
      asm volatile("s_waitcnt vmcnt(4)" ::: "memory");
    } else {
      asm volatile("s_waitcnt vmcnt(0)" ::: "memory");
    }
    __builtin_amdgcn_sched_barrier(0);     // no ds_read hoisting above the waits

    const int jb = slice * 2048 + t * 32;
    float sqc0 = sqL[t * 32 + lc];         // lgkm reads: vmem queue stays pure GLDS
    float sqc1 = sqL[t * 32 + 16 + lc];

    // per cg: 2 ds_reads feed 6 MFMA (2 rowgroups x 3 terms)  (R10 verbatim)
#pragma unroll
    for (int cg = 0; cg < 2; ++cg) {
      f32x4 a0 = {}, a1 = {};
#pragma unroll
      for (int ks = 0; ks < 4; ++ks) {
        bf16x8 bh = BhL[cur][cg * 256 + ks * 64 + lane];
        bf16x8 bl = BlL[cur][cg * 256 + ks * 64 + lane];
        a0 = MFMA16(Ah0[ks], bh, a0);
        a0 = MFMA16(Al0[ks], bh, a0);
        a0 = MFMA16(Ah0[ks], bl, a0);
        a1 = MFMA16(Ah1[ks], bh, a1);
        a1 = MFMA16(Al1[ks], bh, a1);
        a1 = MFMA16(Ah1[ks], bl, a1);
      }
      // epilogue: d = sq_j - 2*dot; ascending cg then t, strict < = first-min.
      // 32-aligned tiles: diagonal only possible when jb == rowlo (wave-uniform).
      const int j = jb + cg * 16 + lc;
      const float sqc = cg ? sqc1 : sqc0;
      if (jb != rowlo) {
#pragma unroll
        for (int r = 0; r < 4; ++r) {
          float d0 = fmaf(-2.0f, a0[r], sqc);
          if (d0 < best0[r]) { best0[r] = d0; bidx0[r] = j; }
          float d1 = fmaf(-2.0f, a1[r], sqc);
          if (d1 < best1[r]) { best1[r] = d1; bidx1[r] = j; }
        }
      } else {
#pragma unroll
        for (int r = 0; r < 4; ++r) {
          float d0 = fmaf(-2.0f, a0[r], sqc);
          if (j != ig0 + r && d0 < best0[r]) { best0[r] = d0; bidx0[r] = j; }
          float d1 = fmaf(-2.0f, a1[r], sqc);
          if (j != ig0 + 16 + r && d1 < best1[r]) { best1[r] = d1; bidx1[r] = j; }
        }
      }
    }

    cur = (cur == 2) ? 0 : cur + 1;
    stg = (stg == 2) ? 0 : stg + 1;
  }

  // cross-lane argmin over the 16 col-lanes sharing each row; lex (d,j) = first-min
#pragma unroll
  for (int r = 0; r < 4; ++r) {
    float d0 = best0[r], d1 = best1[r];
    int i0 = bidx0[r], i1 = bidx1[r];
#pragma unroll
    for (int off = 1; off < 16; off <<= 1) {
      float od = __shfl_xor(d0, off); int oi = __shfl_xor(i0, off);
      if (od < d0 || (od == d0 && oi < i0)) { d0 = od; i0 = oi; }
      od = __shfl_xor(d1, off); oi = __shfl_xor(i1, off);
      if (od < d1 || (od == d1 && oi < i1)) { d1 = od; i1 = oi; }
    }
    if (lc == 0) {  // rows are wave/lane-quad exclusive
      bestD[slice * NN + ig0 + r] = d0;
      bestI[slice * NN + ig0 + r] = i0;
      bestD[slice * NN + ig0 + 16 + r] = d1;
      bestI[slice * NN + ig0 + 16 + r] = i1;
    }
  }
}

// --- merge 8 slices per row, count label matches ---
__global__ __launch_bounds__(256) void combine_kernel(const float* __restrict__ bestD,
                                                      const int* __restrict__ bestI,
                                                      const int* __restrict__ labels,
                                                      int* __restrict__ count) {
  int r = blockIdx.x * 256 + threadIdx.x;
  float d = bestD[r];
  int i = bestI[r];
#pragma unroll
  for (int s = 1; s < 8; ++s) {
    float ds = bestD[s * NN + r];
    int is = bestI[s * NN + r];
    if (ds < d || (ds == d && is < i)) { d = ds; i = is; }
  }
  bool match = (labels[i] == labels[r]);
  unsigned long long mb = __ballot(match);
  if ((threadIdx.x & 63) == 0) atomicAdd(count, (int)__popcll(mb));
}

__global__ void finalize_kernel(const int* __restrict__ count, float* __restrict__ out) {
  out[0] = (float)(*count) * (1.0f / 16384.0f);
}

extern "C" void kernel_launch(void* const* d_in, const int* in_sizes, int n_in,
                              void* d_out, int out_size, void* d_ws, size_t ws_size,
                              hipStream_t stream) {
  const float* feat = (const float*)d_in[0];
  const int* labels = (const int*)d_in[1];
  float* out = (float*)d_out;
  char* ws = (char*)d_ws;

  int* count = (int*)ws;                              // 4 B
  float* sq = (float*)(ws + 1024);                    // 64 KB
  float* bestD = (float*)(ws + (1 << 19));            // 8*N floats = 512 KB
  int* bestI = (int*)(ws + (1 << 20));                // 8*N ints  = 512 KB
  bf16x8* Ph = (bf16x8*)(ws + (2 << 20));             // 4 MB
  bf16x8* Pl = (bf16x8*)(ws + (6 << 20));             // 4 MB   (total 10 MB)

  hipMemsetAsync(count, 0, sizeof(int), stream);
  sq_kernel<<<NN / 4, 256, 0, stream>>>(feat, sq);
  convert_kernel<<<1024, 256, 0, stream>>>(feat, Ph, Pl);
  nn_mfma<<<1024, 256, 0, stream>>>(Ph, Pl, sq, bestD, bestI);
  combine_kernel<<<NN / 256, 256, 0, stream>>>(bestD, bestI, labels, count);
  finalize_kernel<<<1, 1, 0, stream>>>(count, out);
}